// Round 1
// baseline (914.560 us; speedup 1.0000x reference)
//
#include <hip/hip_runtime.h>

// DCKModule: conv1(1x1)+BN+ReLU -> conv2(1x1) -> 7x7 involution + residual
// B=8 C=256 H=W=96, R=64, G=16 GC=16 K=7 PAD=3
#define Bn   8
#define Cn   256
#define Hn   96
#define Wn   96
#define Rn   64
#define Gn   16
#define GCn  16
#define KSn  7
#define HWn  (Hn * Wn)          // 9216
#define BN_EPS 1e-5f

__device__ __forceinline__ unsigned short f2bf(float f) {
    unsigned u = __float_as_uint(f);
    u += 0x7FFFu + ((u >> 16) & 1u);      // round-to-nearest-even
    return (unsigned short)(u >> 16);
}
__device__ __forceinline__ float bf2f(unsigned short h) {
    return __uint_as_float(((unsigned)h) << 16);
}

// ---------------------------------------------------------------------------
// Kernel 1: x[b,o,p] = relu(BN(sum_c W1[o,c]*guide[b,c,p]))
// grid = B * (9216/64) = 1152 blocks, 256 threads.
// Each wave has a uniform 16-output chunk (o0) -> W1 reads are scalar loads;
// guide reads are 64-lane coalesced.
// ---------------------------------------------------------------------------
__global__ __launch_bounds__(256) void k1_conv1_bn_relu(
    const float* __restrict__ guide, const float* __restrict__ W1,
    const float* __restrict__ gamma, const float* __restrict__ beta,
    const float* __restrict__ mean,  const float* __restrict__ var,
    float* __restrict__ xout)
{
    const int t  = threadIdx.x;
    const int bp = blockIdx.x;                 // 0..1151
    const int b  = bp / 144;
    const int px = (bp - b * 144) * 64 + (t & 63);
    const int o0 = __builtin_amdgcn_readfirstlane((t >> 6) * 16);  // wave-uniform

    const float* gb = guide + (size_t)b * Cn * HWn + px;

    float acc[16];
#pragma unroll
    for (int j = 0; j < 16; ++j) acc[j] = 0.f;

    for (int c0 = 0; c0 < Cn; c0 += 32) {
        float gv[32];
#pragma unroll
        for (int cc = 0; cc < 32; ++cc)
            gv[cc] = gb[(size_t)(c0 + cc) * HWn];
#pragma unroll
        for (int j = 0; j < 16; ++j) {
            const float* w1r = W1 + (o0 + j) * Cn + c0;   // uniform -> s_load
#pragma unroll
            for (int cc = 0; cc < 32; ++cc)
                acc[j] = fmaf(w1r[cc], gv[cc], acc[j]);
        }
    }

#pragma unroll
    for (int j = 0; j < 16; ++j) {
        const int o  = o0 + j;
        const float iv = gamma[o] * rsqrtf(var[o] + BN_EPS);
        float v = fmaf(acc[j], iv, beta[o] - mean[o] * iv);
        v = fmaxf(v, 0.f);
        xout[((size_t)b * Rn + o) * HWn + px] = v;
    }
}

// ---------------------------------------------------------------------------
// Kernel 2: fused conv2 + involution + residual.
// grid = B * G * (6*6) = 4608 blocks, 256 threads. Tile = 16x16 pixels.
// Phase A: thread t == pixel t; df[49] in registers (W2 via scalar loads),
//          stored bf16 into LDS.
// Phase B: thread = (gc-quad via wave id, pixel-quad); fm via ds_read_b128,
//          df via ds_read_b64; 16 fp32 accumulators; float4 stores.
// LDS: sFM 16*22*28*4 = 39424 B (stride 28: ph*28 mod 32 gives 2-way max ->
//      free) + sDF 49*256*2 = 25088 B ==> 64512 B, 2 blocks/CU.
// ---------------------------------------------------------------------------
__global__ __launch_bounds__(256) void k2_conv2_involution(
    const float* __restrict__ fm, const float* __restrict__ x,
    const float* __restrict__ W2, float* __restrict__ out)
{
    __shared__ float          sFM[GCn][22][28];
    __shared__ unsigned short sDF[KSn * KSn][256];

    const int t = threadIdx.x;
    int bx = blockIdx.x;
    const int tile = bx % 36;  bx /= 36;
    const int g    = bx % Gn;
    const int b    = bx / Gn;
    const int th0  = (tile / 6) * 16;
    const int tw0  = (tile % 6) * 16;

    // ---- cooperative fm halo-tile load (zero padded) ----
    {
        const float* fmb = fm + (size_t)(b * Cn + g * GCn) * HWn;
        for (int e = t; e < GCn * 22 * 22; e += 256) {
            int gc  = e / 484;
            int rem = e - gc * 484;
            int r   = rem / 22;
            int cc  = rem - r * 22;
            int gh  = th0 + r - 3;
            int gw  = tw0 + cc - 3;
            float v = 0.f;
            if ((unsigned)gh < (unsigned)Hn && (unsigned)gw < (unsigned)Wn)
                v = fmb[(size_t)gc * HWn + gh * Wn + gw];
            sFM[gc][r][cc] = v;
        }
    }

    // ---- phase A: df[49] for pixel t, write bf16 to LDS ----
    {
        const int ph = t >> 4, pw = t & 15;
        const int gh = th0 + ph, gw = tw0 + pw;
        const float* xb = x + (size_t)b * Rn * HWn + gh * Wn + gw;
        float xv[Rn];
#pragma unroll
        for (int c = 0; c < Rn; ++c) xv[c] = xb[(size_t)c * HWn];

        const float* w2g = W2 + (size_t)g * 49 * Rn;   // block-uniform base
        for (int i0 = 0; i0 < 49; i0 += 7) {
            float d[7];
#pragma unroll
            for (int k = 0; k < 7; ++k) d[k] = 0.f;
#pragma unroll
            for (int c = 0; c < Rn; ++c) {
                const float xc = xv[c];
#pragma unroll
                for (int k = 0; k < 7; ++k)
                    d[k] = fmaf(w2g[(i0 + k) * Rn + c], xc, d[k]);  // s_load
            }
#pragma unroll
            for (int k = 0; k < 7; ++k) sDF[i0 + k][t] = f2bf(d[k]);
        }
    }
    __syncthreads();

    // ---- phase B: involution + residual ----
    {
        const int q   = t & 63;
        const int wv  = __builtin_amdgcn_readfirstlane(t >> 6);  // gc quad
        const int ph  = q >> 2;
        const int qw4 = (q & 3) * 4;

        float acc[4][4];
#pragma unroll
        for (int gi = 0; gi < 4; ++gi) {
            const int gc = wv * 4 + gi;
#pragma unroll
            for (int p = 0; p < 4; ++p)
                acc[gi][p] = sFM[gc][ph + 3][qw4 + p + 3];   // residual (exact fp32)
        }

#pragma unroll
        for (int di = 0; di < 7; ++di) {
            const int r = ph + di;
            float df4[7][4];
#pragma unroll
            for (int dj = 0; dj < 7; ++dj) {
                ushort4 u = *(const ushort4*)&sDF[di * 7 + dj][q * 4]; // ds_read_b64
                df4[dj][0] = bf2f(u.x); df4[dj][1] = bf2f(u.y);
                df4[dj][2] = bf2f(u.z); df4[dj][3] = bf2f(u.w);
            }
#pragma unroll
            for (int gi = 0; gi < 4; ++gi) {
                const int gc = wv * 4 + gi;
                const float4 a0 = *(const float4*)&sFM[gc][r][qw4 + 0]; // ds_read_b128
                const float4 a1 = *(const float4*)&sFM[gc][r][qw4 + 4];
                const float4 a2 = *(const float4*)&sFM[gc][r][qw4 + 8];
                const float fmv[12] = {a0.x, a0.y, a0.z, a0.w,
                                       a1.x, a1.y, a1.z, a1.w,
                                       a2.x, a2.y, a2.z, a2.w};
#pragma unroll
                for (int dj = 0; dj < 7; ++dj)
#pragma unroll
                    for (int p = 0; p < 4; ++p)
                        acc[gi][p] = fmaf(fmv[dj + p], df4[dj][p], acc[gi][p]);
            }
        }

#pragma unroll
        for (int gi = 0; gi < 4; ++gi) {
            const int gc = wv * 4 + gi;
            float4 o4 = make_float4(acc[gi][0], acc[gi][1], acc[gi][2], acc[gi][3]);
            *(float4*)&out[((size_t)(b * Cn + g * GCn + gc) * Hn + th0 + ph) * Wn
                           + tw0 + qw4] = o4;
        }
    }
}

// ---------------------------------------------------------------------------
extern "C" void kernel_launch(void* const* d_in, const int* in_sizes, int n_in,
                              void* d_out, int out_size, void* d_ws, size_t ws_size,
                              hipStream_t stream)
{
    const float* fm    = (const float*)d_in[0];
    const float* guide = (const float*)d_in[1];
    const float* W1    = (const float*)d_in[2];
    const float* gamma = (const float*)d_in[3];
    const float* beta  = (const float*)d_in[4];
    const float* mean  = (const float*)d_in[5];
    const float* var   = (const float*)d_in[6];
    const float* W2    = (const float*)d_in[7];
    float* out = (float*)d_out;
    float* x   = (float*)d_ws;   // B*64*9216 fp32 = 18.9 MB

    k1_conv1_bn_relu<<<Bn * (HWn / 64), 256, 0, stream>>>(
        guide, W1, gamma, beta, mean, var, x);

    k2_conv2_involution<<<Bn * Gn * 36, 256, 0, stream>>>(
        fm, x, W2, out);
}

// Round 2
// 647.975 us; speedup vs baseline: 1.4114x; 1.4114x over previous
//
#include <hip/hip_runtime.h>

// DCKModule: conv1(1x1)+BN+ReLU -> conv2(1x1, MFMA bf16) -> 7x7 involution + residual
// B=8 C=256 H=W=96, R=64, G=16 GC=16 K=7 PAD=3
#define Bn   8
#define Cn   256
#define Hn   96
#define Wn   96
#define Rn   64
#define Gn   16
#define GCn  16
#define HWn  (Hn * Wn)          // 9216
#define BN_EPS 1e-5f

typedef short  short8  __attribute__((ext_vector_type(8)));
typedef float  floatx4 __attribute__((ext_vector_type(4)));

__device__ __forceinline__ unsigned short f2bf(float f) {
    unsigned u = __float_as_uint(f);
    u += 0x7FFFu + ((u >> 16) & 1u);      // round-to-nearest-even
    return (unsigned short)(u >> 16);
}
__device__ __forceinline__ float lo2f(unsigned u) { return __uint_as_float(u << 16); }
__device__ __forceinline__ float hi2f(unsigned u) { return __uint_as_float(u & 0xFFFF0000u); }

// ---------------------------------------------------------------------------
// K0: cast W2 [784][64] fp32 -> bf16, zero-pad rows to 816 (phase-A m-tiles
// read up to row g*49+63 = 798 for g=15; pad keeps those finite).
// ---------------------------------------------------------------------------
__global__ __launch_bounds__(256) void k0_cast_w2(
    const float* __restrict__ W2, unsigned short* __restrict__ w2bf)
{
    const int i = blockIdx.x * 256 + threadIdx.x;        // 816*64 = 52224
    if (i < 816 * 64)
        w2bf[i] = (i < 784 * 64) ? f2bf(W2[i]) : (unsigned short)0;
}

// ---------------------------------------------------------------------------
// K1: x_bf[b][px][64] = bf16(relu(BN(sum_c W1[o,c]*guide[b,c,px])))
// grid = 8*144 = 1152 blocks x 256. Wave = 64 px, o-chunk 16 per wave.
// W1/BN via wave-uniform scalar loads; guide coalesced; explicit 16-wide
// double-buffer keeps VGPR low -> 4 waves/SIMD.
// ---------------------------------------------------------------------------
__global__ __launch_bounds__(256, 4) void k1_conv1_bn_relu(
    const float* __restrict__ guide, const float* __restrict__ W1,
    const float* __restrict__ gamma, const float* __restrict__ beta,
    const float* __restrict__ mean,  const float* __restrict__ var,
    unsigned short* __restrict__ xbf)
{
    const int t   = threadIdx.x;
    const int blk = blockIdx.x;
    const int b   = blk / 144;
    const int px  = (blk - b * 144) * 64 + (t & 63);
    const int o0  = __builtin_amdgcn_readfirstlane((t >> 6) * 16);

    const float* gp = guide + b * (Cn * HWn) + px;   // int offsets throughout

    float acc[16];
#pragma unroll
    for (int j = 0; j < 16; ++j) acc[j] = 0.f;

    float bufA[16], bufB[16];
#pragma unroll
    for (int cc = 0; cc < 16; ++cc) bufA[cc] = gp[cc * HWn];

#pragma unroll 1
    for (int c0 = 0; c0 < Cn; c0 += 32) {
#pragma unroll
        for (int cc = 0; cc < 16; ++cc) bufB[cc] = gp[(c0 + 16 + cc) * HWn];
#pragma unroll
        for (int j = 0; j < 16; ++j) {
            const float* w = W1 + (o0 + j) * Cn + c0;        // s_load
#pragma unroll
            for (int cc = 0; cc < 16; ++cc)
                acc[j] = fmaf(w[cc], bufA[cc], acc[j]);
        }
        if (c0 + 32 < Cn) {
#pragma unroll
            for (int cc = 0; cc < 16; ++cc) bufA[cc] = gp[(c0 + 32 + cc) * HWn];
        }
#pragma unroll
        for (int j = 0; j < 16; ++j) {
            const float* w = W1 + (o0 + j) * Cn + c0 + 16;   // s_load
#pragma unroll
            for (int cc = 0; cc < 16; ++cc)
                acc[j] = fmaf(w[cc], bufB[cc], acc[j]);
        }
    }

    unsigned up[8];
#pragma unroll
    for (int j = 0; j < 8; ++j) {
        float v2[2];
#pragma unroll
        for (int h = 0; h < 2; ++h) {
            const int o  = o0 + 2 * j + h;
            const float iv = gamma[o] * rsqrtf(var[o] + BN_EPS);
            float v = fmaf(acc[2 * j + h], iv, beta[o] - mean[o] * iv);
            v2[h] = fmaxf(v, 0.f);
        }
        up[j] = (unsigned)f2bf(v2[0]) | ((unsigned)f2bf(v2[1]) << 16);
    }
    uint4* dst = (uint4*)(xbf + (b * HWn + px) * Rn + o0);
    dst[0] = make_uint4(up[0], up[1], up[2], up[3]);
    dst[1] = make_uint4(up[4], up[5], up[6], up[7]);
}

// ---------------------------------------------------------------------------
// K3: fused conv2 (MFMA) + involution + residual.
// grid = 8*16*36 = 4608 blocks x 256. Tile 16x16 px, one group per block.
// Phase A: df[49][256] = W2bf[g-slice] x x_bf tile via mfma_16x16x32_bf16,
//          residual folded as df[24] += 1. C-frags -> sDF (bf16, stride 264).
// Phase B: involution from bf16 sFM + sDF; fp32 accum; float4 stores.
// LDS: sFM 16*22*28*2 = 19712 + sDF 49*264*2 = 25872 => 45584 B, 3 blk/CU.
// ---------------------------------------------------------------------------
__global__ __launch_bounds__(256, 3) void k3_conv2_involution(
    const float* __restrict__ fm, const unsigned short* __restrict__ xbf,
    const unsigned short* __restrict__ w2bf, float* __restrict__ out)
{
    __shared__ unsigned short sFM[GCn][22][28];
    __shared__ unsigned short sDF[49][264];

    const int t = threadIdx.x;
    int bx = blockIdx.x;
    const int tile = bx % 36;  bx /= 36;
    const int g    = bx & 15;
    const int b    = bx >> 4;
    const int th0  = (tile / 6) * 16;
    const int tw0  = (tile % 6) * 16;

    // ---- stage fm halo tile (bf16) ----
    {
        const float* fmb = fm + (b * Cn + g * GCn) * HWn;
        for (int e = t; e < GCn * 22 * 22; e += 256) {
            const int gc  = e / 484;
            const int rem = e - gc * 484;
            const int r   = rem / 22;
            const int cc  = rem - r * 22;
            const int gh  = th0 + r - 3;
            const int gw  = tw0 + cc - 3;
            float v = 0.f;
            if ((unsigned)gh < (unsigned)Hn && (unsigned)gw < (unsigned)Wn)
                v = fmb[gc * HWn + gh * Wn + gw];
            sFM[gc][r][cc] = f2bf(v);
        }
    }

    // ---- phase A: conv2 via MFMA ----
    {
        const int lane = t & 63;
        const int wv   = t >> 6;
        const int ln   = lane & 15;
        const int quad = lane >> 4;

        // B-frags: x tile, 4 tile-rows per wave. B[k=r][n=px], k = quad*8+j.
        short8 bfr[4][2];
        const unsigned short* xb =
            xbf + ((b * HWn + th0 * Wn + tw0 + ln) * Rn + quad * 8);
#pragma unroll
        for (int j = 0; j < 4; ++j) {
            const unsigned short* p = xb + (wv * 4 + j) * (Wn * Rn);
            bfr[j][0] = *(const short8*)p;
            bfr[j][1] = *(const short8*)(p + 32);
        }

        const unsigned short* wb = w2bf + ((g * 49 + ln) * Rn + quad * 8);
#pragma unroll
        for (int mp = 0; mp < 4; ++mp) {          // m-subtiles (o 16-chunks)
            const short8 af0 = *(const short8*)(wb + mp * 16 * Rn);
            const short8 af1 = *(const short8*)(wb + mp * 16 * Rn + 32);
#pragma unroll
            for (int j = 0; j < 4; ++j) {
                floatx4 acc = {0.f, 0.f, 0.f, 0.f};
                acc = __builtin_amdgcn_mfma_f32_16x16x32_bf16(af0, bfr[j][0], acc, 0, 0, 0);
                acc = __builtin_amdgcn_mfma_f32_16x16x32_bf16(af1, bfr[j][1], acc, 0, 0, 0);
                const int px = (wv * 4 + j) * 16 + ln;     // C col = lane&15
#pragma unroll
                for (int r = 0; r < 4; ++r) {
                    const int m = mp * 16 + quad * 4 + r;  // C row
                    float v = acc[r];
                    if (m == 24) v += 1.0f;                // fold residual into center tap
                    if (m < 49) sDF[m][px] = f2bf(v);
                }
            }
        }
    }
    __syncthreads();

    // ---- phase B: involution ----
    {
        const int q   = t & 63;
        const int wv  = t >> 6;
        const int ph  = q >> 2;
        const int qw4 = (q & 3) * 4;

        float acc[4][4];
#pragma unroll
        for (int gi = 0; gi < 4; ++gi)
#pragma unroll
            for (int p = 0; p < 4; ++p) acc[gi][p] = 0.f;

#pragma unroll
        for (int di = 0; di < 7; ++di) {
            const int r = ph + di;
            float df4[7][4];
#pragma unroll
            for (int dj = 0; dj < 7; ++dj) {
                const uint2 d = *(const uint2*)&sDF[di * 7 + dj][q * 4];
                df4[dj][0] = lo2f(d.x); df4[dj][1] = hi2f(d.x);
                df4[dj][2] = lo2f(d.y); df4[dj][3] = hi2f(d.y);
            }
#pragma unroll
            for (int gi = 0; gi < 4; ++gi) {
                const int gc = wv * 4 + gi;
                const unsigned short* fr = &sFM[gc][r][qw4];
                const uint2 w01 = *(const uint2*)fr;
                const uint2 w23 = *(const uint2*)(fr + 4);
                const uint2 w45 = *(const uint2*)(fr + 8);
                const float c[12] = {
                    lo2f(w01.x), hi2f(w01.x), lo2f(w01.y), hi2f(w01.y),
                    lo2f(w23.x), hi2f(w23.x), lo2f(w23.y), hi2f(w23.y),
                    lo2f(w45.x), hi2f(w45.x), lo2f(w45.y), hi2f(w45.y)};
#pragma unroll
                for (int dj = 0; dj < 7; ++dj)
#pragma unroll
                    for (int p = 0; p < 4; ++p)
                        acc[gi][p] = fmaf(c[dj + p], df4[dj][p], acc[gi][p]);
            }
        }

#pragma unroll
        for (int gi = 0; gi < 4; ++gi) {
            const int gc = wv * 4 + gi;
            float4 o4 = make_float4(acc[gi][0], acc[gi][1], acc[gi][2], acc[gi][3]);
            *(float4*)&out[((b * Cn + g * GCn + gc) * Hn + th0 + ph) * Wn
                           + tw0 + qw4] = o4;
        }
    }
}

// ---------------------------------------------------------------------------
extern "C" void kernel_launch(void* const* d_in, const int* in_sizes, int n_in,
                              void* d_out, int out_size, void* d_ws, size_t ws_size,
                              hipStream_t stream)
{
    const float* fm    = (const float*)d_in[0];
    const float* guide = (const float*)d_in[1];
    const float* W1    = (const float*)d_in[2];
    const float* gamma = (const float*)d_in[3];
    const float* beta  = (const float*)d_in[4];
    const float* mean  = (const float*)d_in[5];
    const float* var   = (const float*)d_in[6];
    const float* W2    = (const float*)d_in[7];
    float* out = (float*)d_out;

    // ws layout: x_bf [8][9216][64] ushort = 9,437,184 B; then W2bf [816][64]
    unsigned short* xbf  = (unsigned short*)d_ws;
    unsigned short* w2bf = (unsigned short*)((char*)d_ws + (size_t)Bn * HWn * Rn * 2);

    k0_cast_w2<<<204, 256, 0, stream>>>(W2, w2bf);
    k1_conv1_bn_relu<<<Bn * 144, 256, 0, stream>>>(
        guide, W1, gamma, beta, mean, var, xbf);
    k3_conv2_involution<<<Bn * Gn * 36, 256, 0, stream>>>(
        fm, xbf, w2bf, out);
}

// Round 4
// 369.833 us; speedup vs baseline: 2.4729x; 1.7521x over previous
//
#include <hip/hip_runtime.h>

// DCKModule: conv1(1x1)+BN+ReLU -> conv2(1x1, MFMA bf16) -> 7x7 involution + residual
// B=8 C=256 H=W=96, R=64, G=16 GC=16 K=7 PAD=3
#define Bn   8
#define Cn   256
#define Hn   96
#define Wn   96
#define Rn   64
#define Gn   16
#define GCn  16
#define HWn  (Hn * Wn)          // 9216
#define BN_EPS 1e-5f

#define STRIPS   12             // strips of 8 output rows
#define SROWS    8
#define FMROWS   14             // SROWS + 6 halo rows
#define FMSTRIDE 104            // col idx = fmcol + 3; 96 + 6 halo + 2 pad
#define NCHUNK   6              // six 16-col chunks per strip
#define DFSTRIDE 136            // 128 px + 8 pad

typedef short  short8  __attribute__((ext_vector_type(8)));
typedef float  floatx4 __attribute__((ext_vector_type(4)));
typedef float  floatx2 __attribute__((ext_vector_type(2)));

__device__ __forceinline__ unsigned short f2bf(float f) {
    unsigned u = __float_as_uint(f);
    u += 0x7FFFu + ((u >> 16) & 1u);      // round-to-nearest-even
    return (unsigned short)(u >> 16);
}
__device__ __forceinline__ float lo2f(unsigned u) { return __uint_as_float(u << 16); }
__device__ __forceinline__ float hi2f(unsigned u) { return __uint_as_float(u & 0xFFFF0000u); }

// ---------------------------------------------------------------------------
// K0: prep — w2bf (784x64 -> bf16, zero-pad to 816 rows), w1T (transpose W1
// to [c][o] fp32), folded BN constants iv/sh.
// ---------------------------------------------------------------------------
__global__ __launch_bounds__(256) void k0_prep(
    const float* __restrict__ W1, const float* __restrict__ W2,
    const float* __restrict__ gamma, const float* __restrict__ beta,
    const float* __restrict__ mean,  const float* __restrict__ var,
    unsigned short* __restrict__ w2bf, float* __restrict__ w1T,
    float* __restrict__ ivp, float* __restrict__ shp)
{
    const int i = blockIdx.x * 256 + threadIdx.x;
    if (i < 816 * 64)
        w2bf[i] = (i < 784 * 64) ? f2bf(W2[i]) : (unsigned short)0;
    const int j = i - 816 * 64;
    if (j >= 0 && j < 256 * 64) {
        const int c = j >> 6, o = j & 63;
        w1T[j] = W1[o * 256 + c];
    }
    const int k = j - 256 * 64;
    if (k >= 0 && k < 64) {
        const float iv = gamma[k] * rsqrtf(var[k] + BN_EPS);
        ivp[k] = iv;
        shp[k] = beta[k] - mean[k] * iv;
    }
}

// ---------------------------------------------------------------------------
// K1: x_bf[b][px][64] = bf16(relu(BN(W1 . guide[.,px])))
// 1 thread = 1 pixel, all 64 outputs in registers. guide read EXACTLY once,
// fully coalesced. W1 via w1T wave-uniform scalar loads. grid 576 x 128.
// ---------------------------------------------------------------------------
__global__ __launch_bounds__(128) void k1_conv1(
    const float* __restrict__ guide, const float* __restrict__ w1T,
    const float* __restrict__ ivp, const float* __restrict__ shp,
    unsigned short* __restrict__ xbf)
{
    const int bx = blockIdx.x;            // 0..575
    const int b  = bx / 72;
    const int px = (bx - b * 72) * 128 + threadIdx.x;
    const float* gp = guide + b * (Cn * HWn) + px;

    float acc[64];
#pragma unroll
    for (int o = 0; o < 64; ++o) acc[o] = 0.f;

#pragma unroll 1
    for (int c0 = 0; c0 < Cn; c0 += 4) {
        const float g0 = gp[(c0 + 0) * HWn];
        const float g1 = gp[(c0 + 1) * HWn];
        const float g2 = gp[(c0 + 2) * HWn];
        const float g3 = gp[(c0 + 3) * HWn];
        const float* w = w1T + c0 * 64;     // uniform -> s_load
#pragma unroll
        for (int o = 0; o < 64; ++o) {
            float a = acc[o];
            a = fmaf(w[o],        g0, a);
            a = fmaf(w[64 + o],   g1, a);
            a = fmaf(w[128 + o],  g2, a);
            a = fmaf(w[192 + o],  g3, a);
            acc[o] = a;
        }
    }

    unsigned up[32];
#pragma unroll
    for (int j = 0; j < 32; ++j) {
        const float v0 = fmaxf(fmaf(acc[2 * j],     ivp[2 * j],     shp[2 * j]),     0.f);
        const float v1 = fmaxf(fmaf(acc[2 * j + 1], ivp[2 * j + 1], shp[2 * j + 1]), 0.f);
        up[j] = (unsigned)f2bf(v0) | ((unsigned)f2bf(v1) << 16);
    }
    uint4* dst = (uint4*)(xbf + (b * HWn + px) * 64);
#pragma unroll
    for (int j = 0; j < 8; ++j)
        dst[j] = make_uint4(up[4 * j], up[4 * j + 1], up[4 * j + 2], up[4 * j + 3]);
}

// ---------------------------------------------------------------------------
// K3: fused conv2 (MFMA) + involution + residual. Full-width 8-row strips.
// grid = 8*12*16 = 1536 (g innermost for L2/L3 x-tile locality), 256 threads.
// Per block: stage fm strip (16gc x 14 rows x 96 cols, bf16, full-line reads),
// then 6 chunks of 16 cols: phase A MFMA df -> sDF (residual folded into tap
// 24), phase B involution, nontemporal float2 stores.
// LDS: sFM 46,592 + sDF 13,328 = 59,920 B -> 2 blocks/CU.
// ---------------------------------------------------------------------------
__global__ __launch_bounds__(256, 2) void k3_main(
    const float* __restrict__ fm, const unsigned short* __restrict__ xbf,
    const unsigned short* __restrict__ w2bf, float* __restrict__ out)
{
    __shared__ unsigned short sFM[GCn][FMROWS][FMSTRIDE];
    __shared__ unsigned short sDF[49][DFSTRIDE];

    int bx = blockIdx.x;
    const int g     = bx & 15;  bx >>= 4;
    const int strip = bx % STRIPS;
    const int b     = bx / STRIPS;
    const int row0  = strip * SROWS;
    const int t     = threadIdx.x;

    // ---- stage fm strip ----
    {
        // zero halo cols: ci 0..2 and 99..103
        for (int e = t; e < GCn * FMROWS * 8; e += 256) {
            const int gc = e / (FMROWS * 8);
            const int rm = e - gc * (FMROWS * 8);
            const int ri = rm >> 3;
            const int z  = rm & 7;
            sFM[gc][ri][(z < 3) ? z : (96 + z)] = 0;
        }
        const float* fb = fm + (b * Cn + g * GCn) * HWn;
        for (int e = t; e < GCn * FMROWS * 24; e += 256) {
            const int gc = e / (FMROWS * 24);
            const int rm = e - gc * (FMROWS * 24);
            const int ri = rm / 24;
            const int c4 = rm - ri * 24;
            const int gr = row0 + ri - 3;
            float4 v = make_float4(0.f, 0.f, 0.f, 0.f);
            if ((unsigned)gr < (unsigned)Hn)
                v = *(const float4*)(fb + gc * HWn + gr * Wn + c4 * 4);
            sFM[gc][ri][3 + c4 * 4 + 0] = f2bf(v.x);
            sFM[gc][ri][3 + c4 * 4 + 1] = f2bf(v.y);
            sFM[gc][ri][3 + c4 * 4 + 2] = f2bf(v.z);
            sFM[gc][ri][3 + c4 * 4 + 3] = f2bf(v.w);
        }
    }

    const int lane = t & 63, wv = t >> 6;
    const int ln   = lane & 15, quad = lane >> 4;

    // W2 A-frags: held in registers across all chunks
    short8 af[4][2];
    {
        const unsigned short* wb = w2bf + (g * 49 + ln) * 64 + quad * 8;
#pragma unroll
        for (int mt = 0; mt < 4; ++mt) {
            af[mt][0] = *(const short8*)(wb + mt * 16 * 64);
            af[mt][1] = *(const short8*)(wb + mt * 16 * 64 + 32);
        }
    }

    const int r_ = lane >> 3;      // phase-B row 0..7
    const int cp = lane & 7;       // phase-B col-pair 0..7

#pragma unroll 1
    for (int ch = 0; ch < NCHUNK; ++ch) {
        const int cb = ch * 16;

        // ---- phase A: df for this chunk via MFMA ----
#pragma unroll
        for (int jj = 0; jj < 2; ++jj) {
            const int nt = wv * 2 + jj;                 // strip-local row
            const unsigned short* xp =
                xbf + ((b * HWn + (row0 + nt) * Wn + cb + ln) * 64 + quad * 8);
            const short8 b0 = *(const short8*)xp;
            const short8 b1 = *(const short8*)(xp + 32);
            const int px = nt * 16 + ln;
#pragma unroll
            for (int mt = 0; mt < 4; ++mt) {
                floatx4 acc = {0.f, 0.f, 0.f, 0.f};
                acc = __builtin_amdgcn_mfma_f32_16x16x32_bf16(af[mt][0], b0, acc, 0, 0, 0);
                acc = __builtin_amdgcn_mfma_f32_16x16x32_bf16(af[mt][1], b1, acc, 0, 0, 0);
#pragma unroll
                for (int rr = 0; rr < 4; ++rr) {
                    const int m = mt * 16 + quad * 4 + rr;
                    float v = acc[rr];
                    if (m == 24) v += 1.0f;             // residual -> center tap
                    if (m < 49) sDF[m][px] = f2bf(v);
                }
            }
        }
        __syncthreads();

        // ---- phase B: involution for this chunk ----
        {
            float acc[4][2];
#pragma unroll
            for (int gi = 0; gi < 4; ++gi) { acc[gi][0] = 0.f; acc[gi][1] = 0.f; }

#pragma unroll
            for (int di = 0; di < 7; ++di) {
                float dfl[7], dfh[7];
#pragma unroll
                for (int dj = 0; dj < 7; ++dj) {
                    const unsigned u = *(const unsigned*)&sDF[di * 7 + dj][r_ * 16 + 2 * cp];
                    dfl[dj] = lo2f(u); dfh[dj] = hi2f(u);
                }
#pragma unroll
                for (int gi = 0; gi < 4; ++gi) {
                    const int gc = wv * 4 + gi;
                    const unsigned* fp = (const unsigned*)&sFM[gc][r_ + di][cb + 2 * cp];
                    const unsigned u0 = fp[0], u1 = fp[1], u2 = fp[2], u3 = fp[3];
                    const float f[8] = {lo2f(u0), hi2f(u0), lo2f(u1), hi2f(u1),
                                        lo2f(u2), hi2f(u2), lo2f(u3), hi2f(u3)};
#pragma unroll
                    for (int dj = 0; dj < 7; ++dj) {
                        acc[gi][0] = fmaf(f[dj],     dfl[dj], acc[gi][0]);
                        acc[gi][1] = fmaf(f[dj + 1], dfh[dj], acc[gi][1]);
                    }
                }
            }
#pragma unroll
            for (int gi = 0; gi < 4; ++gi) {
                const int gc = wv * 4 + gi;
                floatx2 o2 = {acc[gi][0], acc[gi][1]};
                float* op = out + ((b * Cn + g * GCn + gc) * Hn + row0 + r_) * Wn
                            + cb + 2 * cp;
                __builtin_nontemporal_store(o2, (floatx2*)op);
            }
        }
        __syncthreads();
    }
}

// ---------------------------------------------------------------------------
extern "C" void kernel_launch(void* const* d_in, const int* in_sizes, int n_in,
                              void* d_out, int out_size, void* d_ws, size_t ws_size,
                              hipStream_t stream)
{
    const float* fm    = (const float*)d_in[0];
    const float* guide = (const float*)d_in[1];
    const float* W1    = (const float*)d_in[2];
    const float* gamma = (const float*)d_in[3];
    const float* beta  = (const float*)d_in[4];
    const float* mean  = (const float*)d_in[5];
    const float* var   = (const float*)d_in[6];
    const float* W2    = (const float*)d_in[7];
    float* out = (float*)d_out;

    // ws: xbf [8][9216][64] u16 (9,437,184 B) | w2bf [816][64] u16 (104,448 B)
    //     | w1T [256][64] f32 (65,536 B) | iv [64] f32 | sh [64] f32
    char* wsb = (char*)d_ws;
    unsigned short* xbf  = (unsigned short*)wsb;
    unsigned short* w2bf = (unsigned short*)(wsb + 9437184);
    float*          w1T  = (float*)(wsb + 9437184 + 104448);
    float*          ivp  = (float*)(wsb + 9437184 + 104448 + 65536);
    float*          shp  = ivp + 64;

    k0_prep<<<269, 256, 0, stream>>>(W1, W2, gamma, beta, mean, var,
                                     w2bf, w1T, ivp, shp);
    k1_conv1<<<Bn * 72, 128, 0, stream>>>(guide, w1T, ivp, shp, xbf);
    k3_main<<<Bn * STRIPS * Gn, 256, 0, stream>>>(fm, xbf, w2bf, out);
}

// Round 5
// 296.259 us; speedup vs baseline: 3.0870x; 1.2483x over previous
//
#include <hip/hip_runtime.h>

// DCKModule: conv1(1x1 MFMA)+BN+ReLU -> conv2(1x1 MFMA) -> 7x7 involution + residual
// B=8 C=256 H=W=96, R=64, G=16 GC=16 K=7 PAD=3
#define Bn   8
#define Cn   256
#define Hn   96
#define Wn   96
#define Rn   64
#define Gn   16
#define GCn  16
#define HWn  (Hn * Wn)          // 9216
#define BN_EPS 1e-5f

#define STRIPS   12             // strips of 8 output rows
#define SROWS    8
#define FMROWS   14             // SROWS + 6 halo rows
#define FMSTRIDE 104            // col idx = fmcol + 3; 96 + 6 halo + 2 pad
#define NCHUNK   6              // six 16-col chunks per strip
#define DFSTRIDE 136            // 128 px + 8 pad
#define GCH      8              // gc per block (gc-split)

typedef short  short8  __attribute__((ext_vector_type(8)));
typedef float  floatx4 __attribute__((ext_vector_type(4)));
typedef float  floatx2 __attribute__((ext_vector_type(2)));

__device__ __forceinline__ unsigned short f2bf(float f) {
    unsigned u = __float_as_uint(f);
    u += 0x7FFFu + ((u >> 16) & 1u);      // round-to-nearest-even
    return (unsigned short)(u >> 16);
}
__device__ __forceinline__ float lo2f(unsigned u) { return __uint_as_float(u << 16); }
__device__ __forceinline__ float hi2f(unsigned u) { return __uint_as_float(u & 0xFFFF0000u); }

// ---------------------------------------------------------------------------
// K0: prep — w2bf (784x64 -> bf16, zero-pad to 816 rows), w1bf (64x256 bf16,
// same layout as W1 = A-operand [m=o][k=c]), folded BN constants iv/sh.
// ---------------------------------------------------------------------------
__global__ __launch_bounds__(256) void k0_prep(
    const float* __restrict__ W1, const float* __restrict__ W2,
    const float* __restrict__ gamma, const float* __restrict__ beta,
    const float* __restrict__ mean,  const float* __restrict__ var,
    unsigned short* __restrict__ w2bf, unsigned short* __restrict__ w1bf,
    float* __restrict__ ivp, float* __restrict__ shp)
{
    const int i = blockIdx.x * 256 + threadIdx.x;
    if (i < 816 * 64)
        w2bf[i] = (i < 784 * 64) ? f2bf(W2[i]) : (unsigned short)0;
    const int j = i - 816 * 64;
    if (j >= 0 && j < 64 * 256)
        w1bf[j] = f2bf(W1[j]);
    const int k = j - 64 * 256;
    if (k >= 0 && k < 64) {
        const float iv = gamma[k] * rsqrtf(var[k] + BN_EPS);
        ivp[k] = iv;
        shp[k] = beta[k] - mean[k] * iv;
    }
}

// ---------------------------------------------------------------------------
// K1: conv1 via MFMA, no LDS, no barriers. x_bf[b][px][64].
// grid = 8*144 = 1152 blocks x 256. Wave wv handles n-tile px0+wv*16..+15.
// B-frag: 8 strided coalesced fp32 guide loads per k-step, cast bf16 (guide
// read exactly once). A-frag: w1bf rows, L1/L2-hot. M=64 -> 4 m-tiles/wave.
// ---------------------------------------------------------------------------
__global__ __launch_bounds__(256) void k1_conv1_mfma(
    const float* __restrict__ guide, const unsigned short* __restrict__ w1bf,
    const float* __restrict__ ivp, const float* __restrict__ shp,
    unsigned short* __restrict__ xbf)
{
    const int t    = threadIdx.x;
    const int lane = t & 63, wv = t >> 6;
    const int ln   = lane & 15, quad = lane >> 4;
    const int bx   = blockIdx.x;
    const int b    = bx / 144;
    const int px   = (bx - b * 144) * 64 + wv * 16 + ln;

    const float* gp = guide + b * (Cn * HWn) + (quad * 8) * HWn + px;

    floatx4 acc[4];
#pragma unroll
    for (int mt = 0; mt < 4; ++mt) acc[mt] = (floatx4){0.f, 0.f, 0.f, 0.f};

#pragma unroll 2
    for (int c0 = 0; c0 < Cn; c0 += 32) {
        float bv[8];
#pragma unroll
        for (int j = 0; j < 8; ++j) bv[j] = gp[(c0 + j) * HWn];
        short8 bfrag;
#pragma unroll
        for (int j = 0; j < 8; ++j) bfrag[j] = (short)f2bf(bv[j]);
#pragma unroll
        for (int mt = 0; mt < 4; ++mt) {
            const short8 af = *(const short8*)(w1bf + (mt * 16 + ln) * Cn + c0 + quad * 8);
            acc[mt] = __builtin_amdgcn_mfma_f32_16x16x32_bf16(af, bfrag, acc[mt], 0, 0, 0);
        }
    }

    unsigned short* xp = xbf + (b * HWn + px) * 64;
#pragma unroll
    for (int mt = 0; mt < 4; ++mt) {
#pragma unroll
        for (int rp = 0; rp < 2; ++rp) {
            const int o = mt * 16 + quad * 4 + rp * 2;      // C row
            const float v0 = fmaxf(fmaf(acc[mt][rp * 2],     ivp[o],     shp[o]),     0.f);
            const float v1 = fmaxf(fmaf(acc[mt][rp * 2 + 1], ivp[o + 1], shp[o + 1]), 0.f);
            *(unsigned*)(xp + o) = (unsigned)f2bf(v0) | ((unsigned)f2bf(v1) << 16);
        }
    }
}

// ---------------------------------------------------------------------------
// K3: fused conv2 (MFMA) + involution + residual. Full-width 8-row strips,
// gc-split: 8 channels per block, twin blocks per (b,strip,g).
// grid = 8*12*16*2 = 3072, 256 threads.
// LDS: sFM 8*14*104*2 = 23,296 + sDF 13,328 = 36,624 B -> 4 blocks/CU.
// ---------------------------------------------------------------------------
__global__ __launch_bounds__(256, 4) void k3_main(
    const float* __restrict__ fm, const unsigned short* __restrict__ xbf,
    const unsigned short* __restrict__ w2bf, float* __restrict__ out)
{
    __shared__ unsigned short sFM[GCH][FMROWS][FMSTRIDE];
    __shared__ unsigned short sDF[49][DFSTRIDE];

    int bx = blockIdx.x;
    const int half  = bx & 1;   bx >>= 1;
    const int g     = bx & 15;  bx >>= 4;
    const int strip = bx % STRIPS;
    const int b     = bx / STRIPS;
    const int row0  = strip * SROWS;
    const int t     = threadIdx.x;
    const int cbase = g * GCn + half * GCH;       // first global channel

    // ---- stage fm strip (8 gc x 14 rows x 96 cols, bf16) ----
    {
        for (int e = t; e < GCH * FMROWS * 8; e += 256) {   // zero halo cols
            const int gc = e / (FMROWS * 8);
            const int rm = e - gc * (FMROWS * 8);
            const int ri = rm >> 3;
            const int z  = rm & 7;
            sFM[gc][ri][(z < 3) ? z : (96 + z)] = 0;
        }
        const float* fb = fm + (b * Cn + cbase) * HWn;
        for (int e = t; e < GCH * FMROWS * 24; e += 256) {
            const int gc = e / (FMROWS * 24);
            const int rm = e - gc * (FMROWS * 24);
            const int ri = rm / 24;
            const int c4 = rm - ri * 24;
            const int gr = row0 + ri - 3;
            float4 v = make_float4(0.f, 0.f, 0.f, 0.f);
            if ((unsigned)gr < (unsigned)Hn)
                v = *(const float4*)(fb + gc * HWn + gr * Wn + c4 * 4);
            sFM[gc][ri][3 + c4 * 4 + 0] = f2bf(v.x);
            sFM[gc][ri][3 + c4 * 4 + 1] = f2bf(v.y);
            sFM[gc][ri][3 + c4 * 4 + 2] = f2bf(v.z);
            sFM[gc][ri][3 + c4 * 4 + 3] = f2bf(v.w);
        }
    }

    const int lane = t & 63, wv = t >> 6;
    const int ln   = lane & 15, quad = lane >> 4;

    // W2 A-frags: held in registers across all chunks (duplicated on twins)
    short8 af[4][2];
    {
        const unsigned short* wb = w2bf + (g * 49 + ln) * 64 + quad * 8;
#pragma unroll
        for (int mt = 0; mt < 4; ++mt) {
            af[mt][0] = *(const short8*)(wb + mt * 16 * 64);
            af[mt][1] = *(const short8*)(wb + mt * 16 * 64 + 32);
        }
    }

    const int r_ = lane >> 3;      // phase-B row 0..7
    const int cp = lane & 7;       // phase-B col-pair 0..7

#pragma unroll 1
    for (int ch = 0; ch < NCHUNK; ++ch) {
        const int cb = ch * 16;

        // ---- phase A: df for this chunk via MFMA ----
#pragma unroll
        for (int jj = 0; jj < 2; ++jj) {
            const int nt = wv * 2 + jj;                 // strip-local row
            const unsigned short* xp =
                xbf + ((b * HWn + (row0 + nt) * Wn + cb + ln) * 64 + quad * 8);
            const short8 b0 = *(const short8*)xp;
            const short8 b1 = *(const short8*)(xp + 32);
            const int px = nt * 16 + ln;
#pragma unroll
            for (int mt = 0; mt < 4; ++mt) {
                floatx4 acc = {0.f, 0.f, 0.f, 0.f};
                acc = __builtin_amdgcn_mfma_f32_16x16x32_bf16(af[mt][0], b0, acc, 0, 0, 0);
                acc = __builtin_amdgcn_mfma_f32_16x16x32_bf16(af[mt][1], b1, acc, 0, 0, 0);
#pragma unroll
                for (int rr = 0; rr < 4; ++rr) {
                    const int m = mt * 16 + quad * 4 + rr;
                    float v = acc[rr];
                    if (m == 24) v += 1.0f;             // residual -> center tap
                    if (m < 49) sDF[m][px] = f2bf(v);
                }
            }
        }
        __syncthreads();

        // ---- phase B: involution for this chunk (2 gc per thread) ----
        {
            float acc[2][2];
#pragma unroll
            for (int gi = 0; gi < 2; ++gi) { acc[gi][0] = 0.f; acc[gi][1] = 0.f; }

#pragma unroll
            for (int di = 0; di < 7; ++di) {
                float dfl[7], dfh[7];
#pragma unroll
                for (int dj = 0; dj < 7; ++dj) {
                    const unsigned u = *(const unsigned*)&sDF[di * 7 + dj][r_ * 16 + 2 * cp];
                    dfl[dj] = lo2f(u); dfh[dj] = hi2f(u);
                }
#pragma unroll
                for (int gi = 0; gi < 2; ++gi) {
                    const int gc = wv * 2 + gi;
                    const unsigned* fp = (const unsigned*)&sFM[gc][r_ + di][cb + 2 * cp];
                    const unsigned u0 = fp[0], u1 = fp[1], u2 = fp[2], u3 = fp[3];
                    const float f[8] = {lo2f(u0), hi2f(u0), lo2f(u1), hi2f(u1),
                                        lo2f(u2), hi2f(u2), lo2f(u3), hi2f(u3)};
#pragma unroll
                    for (int dj = 0; dj < 7; ++dj) {
                        acc[gi][0] = fmaf(f[dj],     dfl[dj], acc[gi][0]);
                        acc[gi][1] = fmaf(f[dj + 1], dfh[dj], acc[gi][1]);
                    }
                }
            }
#pragma unroll
            for (int gi = 0; gi < 2; ++gi) {
                const int gc = wv * 2 + gi;
                floatx2 o2 = {acc[gi][0], acc[gi][1]};
                float* op = out + ((b * Cn + cbase + gc) * Hn + row0 + r_) * Wn
                            + cb + 2 * cp;
                __builtin_nontemporal_store(o2, (floatx2*)op);
            }
        }
        __syncthreads();
    }
}

// ---------------------------------------------------------------------------
extern "C" void kernel_launch(void* const* d_in, const int* in_sizes, int n_in,
                              void* d_out, int out_size, void* d_ws, size_t ws_size,
                              hipStream_t stream)
{
    const float* fm    = (const float*)d_in[0];
    const float* guide = (const float*)d_in[1];
    const float* W1    = (const float*)d_in[2];
    const float* gamma = (const float*)d_in[3];
    const float* beta  = (const float*)d_in[4];
    const float* mean  = (const float*)d_in[5];
    const float* var   = (const float*)d_in[6];
    const float* W2    = (const float*)d_in[7];
    float* out = (float*)d_out;

    // ws: xbf [8][9216][64] u16 (9,437,184 B) | w2bf [816][64] u16 (104,448 B)
    //     | w1bf [64][256] u16 (32,768 B) | iv [64] f32 | sh [64] f32
    char* wsb = (char*)d_ws;
    unsigned short* xbf  = (unsigned short*)wsb;
    unsigned short* w2bf = (unsigned short*)(wsb + 9437184);
    unsigned short* w1bf = (unsigned short*)(wsb + 9437184 + 104448);
    float*          ivp  = (float*)(wsb + 9437184 + 104448 + 32768);
    float*          shp  = ivp + 64;

    k0_prep<<<269, 256, 0, stream>>>(W1, W2, gamma, beta, mean, var,
                                     w2bf, w1bf, ivp, shp);
    k1_conv1_mfma<<<Bn * 144, 256, 0, stream>>>(guide, w1bf, ivp, shp, xbf);
    k3_main<<<Bn * STRIPS * Gn * 2, 256, 0, stream>>>(fm, xbf, w2bf, out);
}